// Round 1
// baseline (449.774 us; speedup 1.0000x reference)
//
#include <hip/hip_runtime.h>
#include <math.h>

// AWLoss closed-form: f = 24 - (0.5/511^2) * sum_c S1_c^2 / S2_c
// where S1 = sum Re(Fdconv), S2 = sum |Fdconv|^2 over the half-spectrum
// k1 in [0,511), k2 in [0,256) with weight 1 for k2==0 column, 2 otherwise.
// Fdconv = (conj(X)Y + eps*wbar) / (|X|^2 + eps*wbar), wbar = e^{-2pi i (k1+k2)/511}
// X = DFT2(pad(target)), Y = DFT2(pad(recon)); pad offset = 127.

#define NFULL 511
#define PADOFF 127
#define NCH 48
#define ROWS1 16     // rows per stage1 block
#define K1T 16       // k1 values per stage2 block
#define TWO_PI_F 6.283185307179586f
#define EPSV 1e-9f

// ---------------- table generation ----------------
__global__ void gen_tables(float2* __restrict__ w511,
                           float2* __restrict__ w1,
                           float2* __restrict__ w2) {
    int i = blockIdx.x * 256 + threadIdx.x;
    if (i < 511) {
        float a = -TWO_PI_F * (float)i / 511.0f;
        w511[i] = make_float2(cosf(a), sinf(a));
    }
    if (i < 65536) {                 // W1[m][k2], m,k2 in [0,256)
        int m = i >> 8, k2 = i & 255;
        int p = (k2 * (m + PADOFF)) % 511;
        float a = -TWO_PI_F * (float)p / 511.0f;
        w1[i] = make_float2(cosf(a), sinf(a));
    }
    if (i < 511 * 256) {             // W2[k1][n], k1 in [0,511), n in [0,256)
        int k1 = i >> 8, n = i & 255;
        int p = (k1 * (n + PADOFF)) % 511;
        float a = -TWO_PI_F * (float)p / 511.0f;
        w2[i] = make_float2(cosf(a), sinf(a));
    }
}

__global__ void zero_acc(float* __restrict__ s) {
    if (threadIdx.x < 2 * NCH) s[threadIdx.x] = 0.0f;
}

// ---------------- stage 1: DFT along W ----------------
// out X1[img][n1][k2] = sum_b in[n1][b] * w511[(k2*(b+127))%511]
// img in [0, 2*chunk): img>>1 = local channel, img&1: 0=target(X), 1=recon(Y)
__global__ __launch_bounds__(256) void stage1(const float* __restrict__ target,
                                              const float* __restrict__ recon,
                                              const float2* __restrict__ w1,
                                              float2* __restrict__ x1,
                                              int c0) {
    int img = blockIdx.x >> 4;          // 16 row-blocks per image
    int rb  = blockIdx.x & 15;
    int lc  = img >> 1;
    int t   = img & 1;
    const float* src = (t == 0 ? target : recon) + (size_t)(c0 + lc) * 65536;

    __shared__ float xr[ROWS1][256];
    int tid = threadIdx.x;               // = k2
    #pragma unroll
    for (int r = 0; r < ROWS1; ++r)
        xr[r][tid] = src[(rb * ROWS1 + r) * 256 + tid];
    __syncthreads();

    float accr[ROWS1], acci[ROWS1];
    #pragma unroll
    for (int r = 0; r < ROWS1; ++r) { accr[r] = 0.f; acci[r] = 0.f; }

    for (int m = 0; m < 256; ++m) {
        float2 w = w1[m * 256 + tid];
        #pragma unroll
        for (int r = 0; r < ROWS1; ++r) {
            float v = xr[r][m];
            accr[r] = fmaf(v, w.x, accr[r]);
            acci[r] = fmaf(v, w.y, acci[r]);
        }
    }
    float2* dst = x1 + ((size_t)img * 256 + rb * ROWS1) * 256;
    #pragma unroll
    for (int r = 0; r < ROWS1; ++r)
        dst[(size_t)r * 256 + tid] = make_float2(accr[r], acci[r]);
}

// ---------------- stage 2: DFT along H + pointwise + reduce ----------------
__global__ __launch_bounds__(256) void stage2(const float2* __restrict__ x1,
                                              const float2* __restrict__ w2,
                                              const float2* __restrict__ w511,
                                              float* __restrict__ sacc,
                                              int c0) {
    int lc = blockIdx.x >> 5;            // 32 k1-blocks per channel
    int kb = blockIdx.x & 31;
    int k1base = kb * K1T;
    int rows = (511 - k1base < K1T) ? (511 - k1base) : K1T;
    int tid = threadIdx.x;               // = k2

    __shared__ float2 w2s[K1T][256];
    #pragma unroll
    for (int r = 0; r < K1T; ++r) {
        int k1 = k1base + r;
        w2s[r][tid] = (k1 < 511) ? w2[k1 * 256 + tid] : make_float2(0.f, 0.f);
    }
    __syncthreads();

    const float2* xt = x1 + (size_t)(lc * 2 + 0) * 65536;  // target -> X
    const float2* yt = x1 + (size_t)(lc * 2 + 1) * 65536;  // recon  -> Y

    float Xr[K1T], Xi[K1T], Yr[K1T], Yi[K1T];
    #pragma unroll
    for (int r = 0; r < K1T; ++r) { Xr[r]=0.f; Xi[r]=0.f; Yr[r]=0.f; Yi[r]=0.f; }

    for (int n = 0; n < 256; ++n) {
        float2 a = xt[(size_t)n * 256 + tid];
        float2 b = yt[(size_t)n * 256 + tid];
        #pragma unroll
        for (int r = 0; r < K1T; ++r) {
            float2 w = w2s[r][n];
            Xr[r] = fmaf(w.x, a.x, Xr[r]); Xr[r] = fmaf(-w.y, a.y, Xr[r]);
            Xi[r] = fmaf(w.x, a.y, Xi[r]); Xi[r] = fmaf( w.y, a.x, Xi[r]);
            Yr[r] = fmaf(w.x, b.x, Yr[r]); Yr[r] = fmaf(-w.y, b.y, Yr[r]);
            Yi[r] = fmaf(w.x, b.y, Yi[r]); Yi[r] = fmaf( w.y, b.x, Yi[r]);
        }
    }

    float s1 = 0.f, s2 = 0.f;
    float wgt = (tid == 0) ? 1.f : 2.f;
    for (int r = 0; r < rows; ++r) {
        int k1 = k1base + r;
        int p = k1 + tid; if (p >= 511) p -= 511;
        float2 wb = w511[p];
        float Pr = Xr[r]*Yr[r] + Xi[r]*Yi[r];
        float Pi = Xr[r]*Yi[r] - Xi[r]*Yr[r];
        float Q  = Xr[r]*Xr[r] + Xi[r]*Xi[r];
        float nr = Pr + EPSV * wb.x;
        float ni = Pi + EPSV * wb.y;
        float dr = Q  + EPSV * wb.x;
        float di = EPSV * wb.y;
        float inv = 1.0f / (dr*dr + di*di);
        s1 += wgt * (nr*dr + ni*di) * inv;
        s2 += wgt * (nr*nr + ni*ni) * inv;
    }

    // block reduction (4 waves of 64)
    for (int off = 32; off > 0; off >>= 1) {
        s1 += __shfl_down(s1, off);
        s2 += __shfl_down(s2, off);
    }
    __shared__ float red[8];
    int wid = tid >> 6, lane = tid & 63;
    if (lane == 0) { red[wid] = s1; red[4 + wid] = s2; }
    __syncthreads();
    if (tid == 0) {
        float a1 = red[0] + red[1] + red[2] + red[3];
        float a2 = red[4] + red[5] + red[6] + red[7];
        atomicAdd(&sacc[c0 + lc], a1);
        atomicAdd(&sacc[NCH + c0 + lc], a2);
    }
}

__global__ void finalize(const float* __restrict__ s, float* __restrict__ out) {
    int t = threadIdx.x;
    float v = 0.f;
    if (t < NCH) {
        float s1 = s[t], s2 = s[NCH + t];
        v = (s2 != 0.f) ? (s1 * s1) / s2 : 0.f;
    }
    for (int off = 32; off > 0; off >>= 1) v += __shfl_down(v, off);
    if (t == 0) out[0] = 24.0f - 0.5f * v / 261121.0f;
}

// ---------------- launch ----------------
extern "C" void kernel_launch(void* const* d_in, const int* in_sizes, int n_in,
                              void* d_out, int out_size, void* d_ws, size_t ws_size,
                              hipStream_t stream) {
    const float* recon  = (const float*)d_in[0];
    const float* target = (const float*)d_in[1];
    float* out = (float*)d_out;
    char* ws = (char*)d_ws;

    const size_t OFF_W511 = 0;
    const size_t OFF_W1   = 4096;
    const size_t OFF_W2   = OFF_W1 + 524288;            // 256*256*8
    const size_t OFF_S    = OFF_W2 + 1046528 + 512;     // 511*256*8, pad
    const size_t OFF_X1   = OFF_S + 512;

    float2* w511 = (float2*)(ws + OFF_W511);
    float2* w1   = (float2*)(ws + OFF_W1);
    float2* w2   = (float2*)(ws + OFF_W2);
    float*  sacc = (float*)(ws + OFF_S);
    float2* x1   = (float2*)(ws + OFF_X1);

    const size_t perch = 2ull * 256 * 256 * 8;          // 1 MiB per channel (X+Y)
    size_t avail = (ws_size > OFF_X1) ? ws_size - OFF_X1 : 0;
    int chunk = (int)(avail / perch);
    if (chunk > NCH) chunk = NCH;
    if (chunk < 1) chunk = 1;

    gen_tables<<<dim3(511), dim3(256), 0, stream>>>(w511, w1, w2);
    zero_acc<<<dim3(1), dim3(128), 0, stream>>>(sacc);

    for (int c0 = 0; c0 < NCH; c0 += chunk) {
        int cc = (NCH - c0 < chunk) ? (NCH - c0) : chunk;
        stage1<<<dim3(cc * 2 * 16), dim3(256), 0, stream>>>(target, recon, w1, x1, c0);
        stage2<<<dim3(cc * 32), dim3(256), 0, stream>>>(x1, w2, w511, sacc, c0);
    }
    finalize<<<dim3(1), dim3(64), 0, stream>>>(sacc, out);
}

// Round 2
// 145.421 us; speedup vs baseline: 3.0929x; 3.0929x over previous
//
#include <hip/hip_runtime.h>
#include <math.h>

// AWLoss closed-form: f = 24 - (0.5/511^2) * sum_c S1_c^2 / S2_c
// S1 = sum Re(Fdconv), S2 = sum |Fdconv|^2 over half-spectrum k1 in [0,511),
// k2 in [0,256), weight 1 for k2==0 else 2.
// Fdconv = (conj(X)Y + eps*wbar) / (|X|^2 + eps*wbar), wbar = e^{-2pi i (k1+k2)/511}
// X = DFT2(pad(target)), Y = DFT2(pad(recon)), pad offset 127.
// Both DFT stages are MFMA bf16 GEMMs (16x16x32), pointwise+reduce fused into
// stage2's epilogue.

#define NCH 48
#define PADOFF 127
#define TWO_PI_F 6.283185307179586f
#define EPSV 1e-9f

typedef float f32x4 __attribute__((ext_vector_type(4)));
typedef short s16x8 __attribute__((ext_vector_type(8)));
typedef unsigned short u16;

union frag_u { u16 u[8]; s16x8 v; };

__device__ __forceinline__ u16 f2bf(float f) {
    union { float f; unsigned u; } x; x.f = f;
    unsigned r = x.u + 0x7FFFu + ((x.u >> 16) & 1u);
    return (u16)(r >> 16);
}

// ---------------- table generation ----------------
// w511[p]   : f32 twiddle e^{-2pi i p/511}, p in [0,511)
// w1f       : stage1 B fragments [c][t(16)][kk(8)][lane(64)][j(8)] bf16
//             B[k=b][n=k2]: k2 = 16t+(l&15), b = 32kk+8(l>>4)+j
// w2f       : stage2 A fragments [kt(32)][c][kk(8)][lane(64)][j(8)] bf16
//             A[m=k1][k=n]: k1 = 16kt+(l&15), n = 32kk+8(l>>4)+j; 0 if k1>=511
__global__ void gen_tables(float2* __restrict__ w511,
                           u16* __restrict__ w1f,
                           u16* __restrict__ w2f) {
    int i = blockIdx.x * 256 + threadIdx.x;
    if (i < 511) {
        float a = -TWO_PI_F * (float)i / 511.0f;
        w511[i] = make_float2(cosf(a), sinf(a));
    }
    if (i < 131072) {           // w1f: c=(i>>16), t=(i>>12)&15, kk=(i>>9)&7
        int j = i & 7, l = (i >> 3) & 63, kk = (i >> 9) & 7;
        int t = (i >> 12) & 15, c = i >> 16;
        int k2 = 16 * t + (l & 15);
        int b  = 32 * kk + 8 * (l >> 4) + j;
        int p = (k2 * (b + PADOFF)) % 511;
        float a = -TWO_PI_F * (float)p / 511.0f;
        w1f[i] = f2bf(c ? sinf(a) : cosf(a));
    }
    if (i < 262144) {           // w2f: kt=(i>>13), c=(i>>12)&1, kk=(i>>9)&7
        int j = i & 7, l = (i >> 3) & 63, kk = (i >> 9) & 7;
        int c = (i >> 12) & 1, kt = i >> 13;
        int k1 = 16 * kt + (l & 15);
        u16 v = 0;
        if (k1 < 511) {
            int n = 32 * kk + 8 * (l >> 4) + j;
            int p = (k1 * (n + PADOFF)) % 511;
            float a = -TWO_PI_F * (float)p / 511.0f;
            v = f2bf(c ? sinf(a) : cosf(a));
        }
        w2f[i] = v;
    }
}

__global__ void zero_acc(float* __restrict__ s) {
    if (threadIdx.x < 2 * NCH) s[threadIdx.x] = 0.0f;
}

// ---------------- stage 1: DFT along W (MFMA) ----------------
// X1[n1][k2] = sum_b src[n1][b] * W1[b][k2]; stored transposed bf16:
// x1t[img_local][c][k2][n1]. grid = cc*2 images x 16 mt.
__global__ __launch_bounds__(256) void stage1(const float* __restrict__ target,
                                              const float* __restrict__ recon,
                                              const u16* __restrict__ w1f,
                                              u16* __restrict__ x1t,
                                              int c0) {
    int bid = blockIdx.x;
    int img_local = bid >> 4;
    int mt = bid & 15;
    int lc = img_local >> 1;
    int tsel = img_local & 1;
    const float* src = (tsel == 0 ? target : recon) + (size_t)(c0 + lc) * 65536;

    int tid = threadIdx.x;
    int w = tid >> 6, l = tid & 63;
    int lm = l & 15, lh = l >> 4;

    // A fragments: src rows (m = l&15), converted f32->bf16
    frag_u af[8];
    const float* ap = src + (size_t)(mt * 16 + lm) * 256 + 8 * lh;
    #pragma unroll
    for (int kk = 0; kk < 8; ++kk) {
        float4 v0 = *(const float4*)(ap + 32 * kk);
        float4 v1 = *(const float4*)(ap + 32 * kk + 4);
        af[kk].u[0] = f2bf(v0.x); af[kk].u[1] = f2bf(v0.y);
        af[kk].u[2] = f2bf(v0.z); af[kk].u[3] = f2bf(v0.w);
        af[kk].u[4] = f2bf(v1.x); af[kk].u[5] = f2bf(v1.y);
        af[kk].u[6] = f2bf(v1.z); af[kk].u[7] = f2bf(v1.w);
    }

    #pragma unroll
    for (int t4 = 0; t4 < 4; ++t4) {
        int t = 4 * w + t4;
        #pragma unroll
        for (int c = 0; c < 2; ++c) {
            f32x4 acc = {0.f, 0.f, 0.f, 0.f};
            const u16* wp = w1f + (size_t)((c * 16 + t) * 8) * 512 + l * 8;
            #pragma unroll
            for (int kk = 0; kk < 8; ++kk) {
                s16x8 b = *(const s16x8*)(wp + kk * 512);
                acc = __builtin_amdgcn_mfma_f32_16x16x32_bf16(af[kk].v, b, acc, 0, 0, 0);
            }
            // D element (m = 4*lh+r, n = lm): n1 = 16mt+4lh+r, k2 = 16t+lm
            ushort4 o;
            o.x = f2bf(acc[0]); o.y = f2bf(acc[1]);
            o.z = f2bf(acc[2]); o.w = f2bf(acc[3]);
            u16* dst = x1t + (((size_t)img_local * 2 + c) * 256 + (16 * t + lm)) * 256
                     + 16 * mt + 4 * lh;
            *(ushort4*)dst = o;
        }
    }
}

// ---------------- stage 2: DFT along H (MFMA) + pointwise + reduce ----------------
// grid = cc channels x 32 k1-tiles. Each wave: 4 k2-tiles.
__global__ __launch_bounds__(256) void stage2(const u16* __restrict__ x1t,
                                              const u16* __restrict__ w2f,
                                              const float2* __restrict__ w511,
                                              float* __restrict__ sacc,
                                              int c0) {
    int lc = blockIdx.x >> 5;
    int kt = blockIdx.x & 31;
    int tid = threadIdx.x;
    int w = tid >> 6, l = tid & 63;
    int lm = l & 15, lh = l >> 4;

    __shared__ float2 w511s[511];
    __shared__ float red[8];
    for (int i = tid; i < 511; i += 256) w511s[i] = w511[i];
    __syncthreads();

    const u16* base = x1t + (size_t)(4 * lc) * 65536;   // planes: Xr,Xi,Yr,Yi
    const u16* wpa  = w2f + (size_t)(kt * 2) * 4096 + l * 8;  // [kt][c][kk][l][j]

    float s1 = 0.f, s2 = 0.f;

    #pragma unroll
    for (int t4 = 0; t4 < 4; ++t4) {
        int t = 4 * w + t4;
        f32x4 crr = {0,0,0,0}, cii = {0,0,0,0}, cri = {0,0,0,0}, cir = {0,0,0,0};
        f32x4 drr = {0,0,0,0}, dii = {0,0,0,0}, dri = {0,0,0,0}, dir = {0,0,0,0};
        size_t roff = (size_t)(16 * t + lm) * 256 + 8 * lh;
        #pragma unroll
        for (int kk = 0; kk < 8; ++kk) {
            s16x8 wr = *(const s16x8*)(wpa + kk * 512);
            s16x8 wi = *(const s16x8*)(wpa + 4096 + kk * 512);
            size_t off = roff + 32 * kk;
            s16x8 ar = *(const s16x8*)(base + off);
            s16x8 ai = *(const s16x8*)(base + 65536 + off);
            s16x8 br = *(const s16x8*)(base + 131072 + off);
            s16x8 bi = *(const s16x8*)(base + 196608 + off);
            crr = __builtin_amdgcn_mfma_f32_16x16x32_bf16(wr, ar, crr, 0, 0, 0);
            cii = __builtin_amdgcn_mfma_f32_16x16x32_bf16(wi, ai, cii, 0, 0, 0);
            cri = __builtin_amdgcn_mfma_f32_16x16x32_bf16(wr, ai, cri, 0, 0, 0);
            cir = __builtin_amdgcn_mfma_f32_16x16x32_bf16(wi, ar, cir, 0, 0, 0);
            drr = __builtin_amdgcn_mfma_f32_16x16x32_bf16(wr, br, drr, 0, 0, 0);
            dii = __builtin_amdgcn_mfma_f32_16x16x32_bf16(wi, bi, dii, 0, 0, 0);
            dri = __builtin_amdgcn_mfma_f32_16x16x32_bf16(wr, bi, dri, 0, 0, 0);
            dir = __builtin_amdgcn_mfma_f32_16x16x32_bf16(wi, br, dir, 0, 0, 0);
        }
        int k2 = 16 * t + lm;
        float wgt = (k2 == 0) ? 1.f : 2.f;
        #pragma unroll
        for (int r = 0; r < 4; ++r) {
            int k1 = 16 * kt + 4 * lh + r;
            if (k1 < 511) {
                float Xr = crr[r] - cii[r], Xi = cri[r] + cir[r];
                float Yr = drr[r] - dii[r], Yi = dri[r] + dir[r];
                int p = k1 + k2; if (p >= 511) p -= 511;
                float2 wb = w511s[p];
                float Pr = Xr * Yr + Xi * Yi;
                float Pi = Xr * Yi - Xi * Yr;
                float Q  = Xr * Xr + Xi * Xi;
                float nr = Pr + EPSV * wb.x;
                float ni = Pi + EPSV * wb.y;
                float dr_ = Q + EPSV * wb.x;
                float di_ = EPSV * wb.y;
                float inv = 1.0f / (dr_ * dr_ + di_ * di_);
                s1 += wgt * (nr * dr_ + ni * di_) * inv;
                s2 += wgt * (nr * nr + ni * ni) * inv;
            }
        }
    }

    #pragma unroll
    for (int off = 32; off > 0; off >>= 1) {
        s1 += __shfl_down(s1, off);
        s2 += __shfl_down(s2, off);
    }
    if (l == 0) { red[w] = s1; red[4 + w] = s2; }
    __syncthreads();
    if (tid == 0) {
        float a1 = red[0] + red[1] + red[2] + red[3];
        float a2 = red[4] + red[5] + red[6] + red[7];
        atomicAdd(&sacc[c0 + lc], a1);
        atomicAdd(&sacc[NCH + c0 + lc], a2);
    }
}

__global__ void finalize(const float* __restrict__ s, float* __restrict__ out) {
    int t = threadIdx.x;
    float v = 0.f;
    if (t < NCH) {
        float s1 = s[t], s2 = s[NCH + t];
        v = (s2 != 0.f) ? (s1 * s1) / s2 : 0.f;
    }
    for (int off = 32; off > 0; off >>= 1) v += __shfl_down(v, off);
    if (t == 0) out[0] = 24.0f - 0.5f * v / 261121.0f;
}

// ---------------- launch ----------------
extern "C" void kernel_launch(void* const* d_in, const int* in_sizes, int n_in,
                              void* d_out, int out_size, void* d_ws, size_t ws_size,
                              hipStream_t stream) {
    const float* recon  = (const float*)d_in[0];
    const float* target = (const float*)d_in[1];
    float* out = (float*)d_out;
    char* ws = (char*)d_ws;

    const size_t OFF_W511 = 0;                       // 4096 B
    const size_t OFF_W1F  = 4096;                    // 262144 B
    const size_t OFF_W2F  = OFF_W1F + 262144;        // 524288 B
    const size_t OFF_S    = OFF_W2F + 524288;        // 512 B
    const size_t OFF_X1   = OFF_S + 512;

    float2* w511 = (float2*)(ws + OFF_W511);
    u16*    w1f  = (u16*)(ws + OFF_W1F);
    u16*    w2f  = (u16*)(ws + OFF_W2F);
    float*  sacc = (float*)(ws + OFF_S);
    u16*    x1t  = (u16*)(ws + OFF_X1);

    const size_t perch = 4ull * 65536 * 2;           // 512 KiB per channel (X+Y, r+i)
    size_t avail = (ws_size > OFF_X1) ? ws_size - OFF_X1 : 0;
    int chunk = (int)(avail / perch);
    if (chunk > NCH) chunk = NCH;
    if (chunk < 1) chunk = 1;

    gen_tables<<<dim3(1024), dim3(256), 0, stream>>>(w511, w1f, w2f);
    zero_acc<<<dim3(1), dim3(128), 0, stream>>>(sacc);

    for (int c0 = 0; c0 < NCH; c0 += chunk) {
        int cc = (NCH - c0 < chunk) ? (NCH - c0) : chunk;
        stage1<<<dim3(cc * 32), dim3(256), 0, stream>>>(target, recon, w1f, x1t, c0);
        stage2<<<dim3(cc * 32), dim3(256), 0, stream>>>(x1t, w2f, w511, sacc, c0);
    }
    finalize<<<dim3(1), dim3(64), 0, stream>>>(sacc, out);
}

// Round 3
// 93.518 us; speedup vs baseline: 4.8095x; 1.5550x over previous
//
#include <hip/hip_runtime.h>
#include <math.h>

// AWLoss closed-form: f = 24 - (0.5/511^2) * sum_c S1_c^2 / S2_c
// S1 = sum Re(Fdconv), S2 = sum |Fdconv|^2 over half-spectrum k1 in [0,511),
// k2 in [0,256), weight 1 for k2==0 else 2.
// Fdconv = (conj(X)Y + eps*wbar) / (|X|^2 + eps*wbar), wbar = e^{-2pi i (k1+k2)/511}
// X = DFT2(pad(target)), Y = DFT2(pad(recon)), pad offset 127.
// Both DFT stages are MFMA bf16 GEMMs (16x16x32); stage2 keeps its x1 slice
// register-stationary and streams the channel-independent w2f twiddles (L2).

#define NCH 48
#define PADOFF 127
#define TWO_PI_F 6.283185307179586f
#define EPSV 1e-9f

typedef float f32x4 __attribute__((ext_vector_type(4)));
typedef short s16x8 __attribute__((ext_vector_type(8)));
typedef unsigned short u16;

union frag_u { u16 u[8]; s16x8 v; };

__device__ __forceinline__ u16 f2bf(float f) {
    union { float f; unsigned u; } x; x.f = f;
    unsigned r = x.u + 0x7FFFu + ((x.u >> 16) & 1u);
    return (u16)(r >> 16);
}

// ---------------- table generation ----------------
__global__ void gen_w511(float2* __restrict__ w511) {
    int i = blockIdx.x * 256 + threadIdx.x;
    if (i < 511) {
        float a = -TWO_PI_F * (float)i / 511.0f;
        w511[i] = make_float2(cosf(a), sinf(a));
    }
}

// w1f : stage1 B fragments [c][t(16)][kk(8)][lane(64)][j(8)] bf16
//       B[k=b][n=k2]: k2 = 16t+(l&15), b = 32kk+8(l>>4)+j
// w2f : stage2 A fragments [kt(32)][c][kk(8)][lane(64)][j(8)] bf16
//       A[m=k1][k=n]: k1 = 16kt+(l&15), n = 32kk+8(l>>4)+j; 0 if k1>=511
__global__ __launch_bounds__(256) void gen_frags(const float2* __restrict__ w511,
                                                 u16* __restrict__ w1f,
                                                 u16* __restrict__ w2f) {
    __shared__ float cs[511], sn[511];
    int tid = threadIdx.x;
    for (int i = tid; i < 511; i += 256) {
        float2 v = w511[i];
        cs[i] = v.x; sn[i] = v.y;
    }
    __syncthreads();
    int i = blockIdx.x * 256 + tid;      // i < 262144
    {
        int j = i & 7, l = (i >> 3) & 63, kk = (i >> 9) & 7;
        int c = (i >> 12) & 1, kt = i >> 13;
        int k1 = 16 * kt + (l & 15);
        u16 v = 0;
        if (k1 < 511) {
            int n = 32 * kk + 8 * (l >> 4) + j;
            int p = (k1 * (n + PADOFF)) % 511;
            v = f2bf(c ? sn[p] : cs[p]);
        }
        w2f[i] = v;
    }
    if (i < 131072) {
        int j = i & 7, l = (i >> 3) & 63, kk = (i >> 9) & 7;
        int t = (i >> 12) & 15, c = i >> 16;
        int k2 = 16 * t + (l & 15);
        int b  = 32 * kk + 8 * (l >> 4) + j;
        int p = (k2 * (b + PADOFF)) % 511;
        w1f[i] = f2bf(c ? sn[p] : cs[p]);
    }
}

__global__ void zero_acc(float* __restrict__ s) {
    if (threadIdx.x < 2 * NCH) s[threadIdx.x] = 0.0f;
}

// ---------------- stage 1: DFT along W (MFMA) ----------------
// X1[n1][k2] = sum_b src[n1][b] * W1[b][k2]; stored transposed bf16:
// x1t[img_local][c][k2][n1]. grid = cc*2 images x 16 mt.
__global__ __launch_bounds__(256) void stage1(const float* __restrict__ target,
                                              const float* __restrict__ recon,
                                              const u16* __restrict__ w1f,
                                              u16* __restrict__ x1t,
                                              int c0) {
    int bid = blockIdx.x;
    int img_local = bid >> 4;
    int mt = bid & 15;
    int lc = img_local >> 1;
    int tsel = img_local & 1;
    const float* src = (tsel == 0 ? target : recon) + (size_t)(c0 + lc) * 65536;

    int tid = threadIdx.x;
    int w = tid >> 6, l = tid & 63;
    int lm = l & 15, lh = l >> 4;

    frag_u af[8];
    const float* ap = src + (size_t)(mt * 16 + lm) * 256 + 8 * lh;
    #pragma unroll
    for (int kk = 0; kk < 8; ++kk) {
        float4 v0 = *(const float4*)(ap + 32 * kk);
        float4 v1 = *(const float4*)(ap + 32 * kk + 4);
        af[kk].u[0] = f2bf(v0.x); af[kk].u[1] = f2bf(v0.y);
        af[kk].u[2] = f2bf(v0.z); af[kk].u[3] = f2bf(v0.w);
        af[kk].u[4] = f2bf(v1.x); af[kk].u[5] = f2bf(v1.y);
        af[kk].u[6] = f2bf(v1.z); af[kk].u[7] = f2bf(v1.w);
    }

    #pragma unroll
    for (int t4 = 0; t4 < 4; ++t4) {
        int t = 4 * w + t4;
        #pragma unroll
        for (int c = 0; c < 2; ++c) {
            f32x4 acc = {0.f, 0.f, 0.f, 0.f};
            const u16* wp = w1f + (size_t)((c * 16 + t) * 8) * 512 + l * 8;
            #pragma unroll
            for (int kk = 0; kk < 8; ++kk) {
                s16x8 b = *(const s16x8*)(wp + kk * 512);
                acc = __builtin_amdgcn_mfma_f32_16x16x32_bf16(af[kk].v, b, acc, 0, 0, 0);
            }
            ushort4 o;
            o.x = f2bf(acc[0]); o.y = f2bf(acc[1]);
            o.z = f2bf(acc[2]); o.w = f2bf(acc[3]);
            u16* dst = x1t + (((size_t)img_local * 2 + c) * 256 + (16 * t + lm)) * 256
                     + 16 * mt + 4 * lh;
            *(ushort4*)dst = o;
        }
    }
}

// ---------------- stage 2: DFT along H (MFMA) + pointwise + reduce ----------------
// grid = cc channels x 16 k2-tiles. Block keeps its x1 slice in registers,
// loops over all 32 k1-tiles (8 per wave), streaming w2f from L2.
__global__ __launch_bounds__(256) void stage2(const u16* __restrict__ x1t,
                                              const u16* __restrict__ w2f,
                                              const float2* __restrict__ w511,
                                              float* __restrict__ sacc,
                                              int c0) {
    int lc = blockIdx.x >> 4;
    int t  = blockIdx.x & 15;
    int tid = threadIdx.x;
    int w = tid >> 6, l = tid & 63;
    int lm = l & 15, lh = l >> 4;

    __shared__ float2 w511s[511];
    __shared__ float red[8];
    for (int i = tid; i < 511; i += 256) w511s[i] = w511[i];
    __syncthreads();

    const u16* base = x1t + (size_t)(4 * lc) * 65536;   // planes: Xr,Xi,Yr,Yi
    size_t roff = (size_t)(16 * t + lm) * 256 + 8 * lh;

    // B fragments (this block's k2-tile, all n), register-stationary
    s16x8 ar[8], ai[8], br[8], bi[8];
    #pragma unroll
    for (int kk = 0; kk < 8; ++kk) {
        size_t off = roff + 32 * kk;
        ar[kk] = *(const s16x8*)(base + off);
        ai[kk] = *(const s16x8*)(base + 65536 + off);
        br[kk] = *(const s16x8*)(base + 131072 + off);
        bi[kk] = *(const s16x8*)(base + 196608 + off);
    }

    int k2 = 16 * t + lm;
    float wgt = (k2 == 0) ? 1.f : 2.f;
    float s1 = 0.f, s2 = 0.f;

    for (int i8 = 0; i8 < 8; ++i8) {
        int kt = 8 * w + i8;
        const u16* wpa = w2f + (size_t)(kt * 2) * 4096 + l * 8;
        f32x4 crr = {0,0,0,0}, cii = {0,0,0,0}, cri = {0,0,0,0}, cir = {0,0,0,0};
        f32x4 drr = {0,0,0,0}, dii = {0,0,0,0}, dri = {0,0,0,0}, dir = {0,0,0,0};
        #pragma unroll
        for (int kk = 0; kk < 8; ++kk) {
            s16x8 wr = *(const s16x8*)(wpa + kk * 512);
            s16x8 wi = *(const s16x8*)(wpa + 4096 + kk * 512);
            crr = __builtin_amdgcn_mfma_f32_16x16x32_bf16(wr, ar[kk], crr, 0, 0, 0);
            cii = __builtin_amdgcn_mfma_f32_16x16x32_bf16(wi, ai[kk], cii, 0, 0, 0);
            cri = __builtin_amdgcn_mfma_f32_16x16x32_bf16(wr, ai[kk], cri, 0, 0, 0);
            cir = __builtin_amdgcn_mfma_f32_16x16x32_bf16(wi, ar[kk], cir, 0, 0, 0);
            drr = __builtin_amdgcn_mfma_f32_16x16x32_bf16(wr, br[kk], drr, 0, 0, 0);
            dii = __builtin_amdgcn_mfma_f32_16x16x32_bf16(wi, bi[kk], dii, 0, 0, 0);
            dri = __builtin_amdgcn_mfma_f32_16x16x32_bf16(wr, bi[kk], dri, 0, 0, 0);
            dir = __builtin_amdgcn_mfma_f32_16x16x32_bf16(wi, br[kk], dir, 0, 0, 0);
        }
        #pragma unroll
        for (int r = 0; r < 4; ++r) {
            int k1 = 16 * kt + 4 * lh + r;
            if (k1 < 511) {
                float Xr = crr[r] - cii[r], Xi = cri[r] + cir[r];
                float Yr = drr[r] - dii[r], Yi = dri[r] + dir[r];
                int p = k1 + k2; if (p >= 511) p -= 511;
                float2 wb = w511s[p];
                float Pr = Xr * Yr + Xi * Yi;
                float Pi = Xr * Yi - Xi * Yr;
                float Q  = Xr * Xr + Xi * Xi;
                float nr = Pr + EPSV * wb.x;
                float ni = Pi + EPSV * wb.y;
                float dr_ = Q + EPSV * wb.x;
                float di_ = EPSV * wb.y;
                float inv = 1.0f / (dr_ * dr_ + di_ * di_);
                s1 += wgt * (nr * dr_ + ni * di_) * inv;
                s2 += wgt * (nr * nr + ni * ni) * inv;
            }
        }
    }

    #pragma unroll
    for (int off = 32; off > 0; off >>= 1) {
        s1 += __shfl_down(s1, off);
        s2 += __shfl_down(s2, off);
    }
    if (l == 0) { red[w] = s1; red[4 + w] = s2; }
    __syncthreads();
    if (tid == 0) {
        float a1 = red[0] + red[1] + red[2] + red[3];
        float a2 = red[4] + red[5] + red[6] + red[7];
        atomicAdd(&sacc[c0 + lc], a1);
        atomicAdd(&sacc[NCH + c0 + lc], a2);
    }
}

__global__ void finalize(const float* __restrict__ s, float* __restrict__ out) {
    int t = threadIdx.x;
    float v = 0.f;
    if (t < NCH) {
        float s1 = s[t], s2 = s[NCH + t];
        v = (s2 != 0.f) ? (s1 * s1) / s2 : 0.f;
    }
    for (int off = 32; off > 0; off >>= 1) v += __shfl_down(v, off);
    if (t == 0) out[0] = 24.0f - 0.5f * v / 261121.0f;
}

// ---------------- launch ----------------
extern "C" void kernel_launch(void* const* d_in, const int* in_sizes, int n_in,
                              void* d_out, int out_size, void* d_ws, size_t ws_size,
                              hipStream_t stream) {
    const float* recon  = (const float*)d_in[0];
    const float* target = (const float*)d_in[1];
    float* out = (float*)d_out;
    char* ws = (char*)d_ws;

    const size_t OFF_W511 = 0;                       // 4096 B
    const size_t OFF_W1F  = 4096;                    // 262144 B
    const size_t OFF_W2F  = OFF_W1F + 262144;        // 524288 B
    const size_t OFF_S    = OFF_W2F + 524288;        // 512 B
    const size_t OFF_X1   = OFF_S + 512;

    float2* w511 = (float2*)(ws + OFF_W511);
    u16*    w1f  = (u16*)(ws + OFF_W1F);
    u16*    w2f  = (u16*)(ws + OFF_W2F);
    float*  sacc = (float*)(ws + OFF_S);
    u16*    x1t  = (u16*)(ws + OFF_X1);

    const size_t perch = 4ull * 65536 * 2;           // 512 KiB per channel
    size_t avail = (ws_size > OFF_X1) ? ws_size - OFF_X1 : 0;
    int chunk = (int)(avail / perch);
    if (chunk > NCH) chunk = NCH;
    if (chunk < 1) chunk = 1;

    gen_w511<<<dim3(2), dim3(256), 0, stream>>>(w511);
    gen_frags<<<dim3(1024), dim3(256), 0, stream>>>(w511, w1f, w2f);
    zero_acc<<<dim3(1), dim3(128), 0, stream>>>(sacc);

    for (int c0 = 0; c0 < NCH; c0 += chunk) {
        int cc = (NCH - c0 < chunk) ? (NCH - c0) : chunk;
        stage1<<<dim3(cc * 32), dim3(256), 0, stream>>>(target, recon, w1f, x1t, c0);
        stage2<<<dim3(cc * 16), dim3(256), 0, stream>>>(x1t, w2f, w511, sacc, c0);
    }
    finalize<<<dim3(1), dim3(64), 0, stream>>>(sacc, out);
}

// Round 4
// 89.780 us; speedup vs baseline: 5.0097x; 1.0416x over previous
//
#include <hip/hip_runtime.h>
#include <math.h>

// AWLoss closed-form: f = 24 - (0.5/511^2) * sum_c S1_c^2 / S2_c
// S1 = sum Re(Fdconv), S2 = sum |Fdconv|^2 over half-spectrum k1 in [0,511),
// k2 in [0,256), weight 1 for k2==0 else 2.
// Fdconv = (conj(X)Y + eps*wbar) / (|X|^2 + eps*wbar), wbar = e^{-2pi i (k1+k2)/511}
// X = DFT2(pad(target)), Y = DFT2(pad(recon)), pad offset 127.
// Both DFT stages are MFMA bf16 GEMMs (16x16x32). stage2 keeps its x1 slice
// register-stationary (asm-pinned so the compiler cannot sink the loads back
// into the loop) and streams channel-independent w2f twiddles from L2.

#define NCH 48
#define PADOFF 127
#define TWO_PI_F 6.283185307179586f
#define EPSV 1e-9f

typedef float f32x4 __attribute__((ext_vector_type(4)));
typedef short s16x8 __attribute__((ext_vector_type(8)));
typedef unsigned short u16;

union frag_u { u16 u[8]; s16x8 v; };

__device__ __forceinline__ u16 f2bf(float f) {
    union { float f; unsigned u; } x; x.f = f;
    unsigned r = x.u + 0x7FFFu + ((x.u >> 16) & 1u);
    return (u16)(r >> 16);
}

// ---------------- setup: twiddle tables + fragment tables + acc zero ----------------
// w1f : stage1 B fragments [c][t(16)][kk(8)][lane(64)][j(8)] bf16
//       B[k=b][n=k2]: k2 = 16t+(l&15), b = 32kk+8(l>>4)+j
// w2f : stage2 A fragments [kt(32)][c][kk(8)][lane(64)][j(8)] bf16
//       A[m=k1][k=n]: k1 = 16kt+(l&15), n = 32kk+8(l>>4)+j; 0 if k1>=511
// w511[p] : f32 e^{-2pi i p/511}
__global__ __launch_bounds__(256) void setup(u16* __restrict__ w1f,
                                             u16* __restrict__ w2f,
                                             float2* __restrict__ w511,
                                             float* __restrict__ sacc) {
    __shared__ float cs[511], sn[511];
    int tid = threadIdx.x;
    for (int i = tid; i < 511; i += 256) {
        float a = -TWO_PI_F * (float)i / 511.0f;
        cs[i] = cosf(a);
        sn[i] = sinf(a);
    }
    __syncthreads();

    int i = blockIdx.x * 256 + tid;      // i < 262144
    {
        int j = i & 7, l = (i >> 3) & 63, kk = (i >> 9) & 7;
        int c = (i >> 12) & 1, kt = i >> 13;
        int k1 = 16 * kt + (l & 15);
        u16 v = 0;
        if (k1 < 511) {
            int n = 32 * kk + 8 * (l >> 4) + j;
            int p = (k1 * (n + PADOFF)) % 511;
            v = f2bf(c ? sn[p] : cs[p]);
        }
        w2f[i] = v;
    }
    if (i < 131072) {
        int j = i & 7, l = (i >> 3) & 63, kk = (i >> 9) & 7;
        int t = (i >> 12) & 15, c = i >> 16;
        int k2 = 16 * t + (l & 15);
        int b  = 32 * kk + 8 * (l >> 4) + j;
        int p = (k2 * (b + PADOFF)) % 511;
        w1f[i] = f2bf(c ? sn[p] : cs[p]);
    }
    if (blockIdx.x == 0 && tid < 2 * NCH) sacc[tid] = 0.0f;
    if (blockIdx.x == 1) {
        for (int p = tid; p < 511; p += 256)
            w511[p] = make_float2(cs[p], sn[p]);
    }
}

// ---------------- stage 1: DFT along W (MFMA) ----------------
// X1[n1][k2] = sum_b src[n1][b] * W1[b][k2]; stored transposed bf16:
// x1t[img_local][c][k2][n1]. grid = cc*2 images x 16 mt.
__global__ __launch_bounds__(256) void stage1(const float* __restrict__ target,
                                              const float* __restrict__ recon,
                                              const u16* __restrict__ w1f,
                                              u16* __restrict__ x1t,
                                              int c0) {
    int bid = blockIdx.x;
    int img_local = bid >> 4;
    int mt = bid & 15;
    int lc = img_local >> 1;
    int tsel = img_local & 1;
    const float* src = (tsel == 0 ? target : recon) + (size_t)(c0 + lc) * 65536;

    int tid = threadIdx.x;
    int w = tid >> 6, l = tid & 63;
    int lm = l & 15, lh = l >> 4;

    frag_u af[8];
    const float* ap = src + (size_t)(mt * 16 + lm) * 256 + 8 * lh;
    #pragma unroll
    for (int kk = 0; kk < 8; ++kk) {
        float4 v0 = *(const float4*)(ap + 32 * kk);
        float4 v1 = *(const float4*)(ap + 32 * kk + 4);
        af[kk].u[0] = f2bf(v0.x); af[kk].u[1] = f2bf(v0.y);
        af[kk].u[2] = f2bf(v0.z); af[kk].u[3] = f2bf(v0.w);
        af[kk].u[4] = f2bf(v1.x); af[kk].u[5] = f2bf(v1.y);
        af[kk].u[6] = f2bf(v1.z); af[kk].u[7] = f2bf(v1.w);
    }

    #pragma unroll
    for (int t4 = 0; t4 < 4; ++t4) {
        int t = 4 * w + t4;
        #pragma unroll
        for (int c = 0; c < 2; ++c) {
            f32x4 acc = {0.f, 0.f, 0.f, 0.f};
            const u16* wp = w1f + (size_t)((c * 16 + t) * 8) * 512 + l * 8;
            #pragma unroll
            for (int kk = 0; kk < 8; ++kk) {
                s16x8 b = *(const s16x8*)(wp + kk * 512);
                acc = __builtin_amdgcn_mfma_f32_16x16x32_bf16(af[kk].v, b, acc, 0, 0, 0);
            }
            ushort4 o;
            o.x = f2bf(acc[0]); o.y = f2bf(acc[1]);
            o.z = f2bf(acc[2]); o.w = f2bf(acc[3]);
            u16* dst = x1t + (((size_t)img_local * 2 + c) * 256 + (16 * t + lm)) * 256
                     + 16 * mt + 4 * lh;
            *(ushort4*)dst = o;
        }
    }
}

// ---------------- stage 2: DFT along H (MFMA) + pointwise + reduce ----------------
// grid = cc channels x 16 k2-tiles. Block keeps its x1 slice in registers
// (pinned), loops over all 32 k1-tiles (8 per wave), streaming w2f from L2.
__global__ __launch_bounds__(256, 2) void stage2(const u16* __restrict__ x1t,
                                                 const u16* __restrict__ w2f,
                                                 const float2* __restrict__ w511,
                                                 float* __restrict__ sacc,
                                                 int c0) {
    int lc = blockIdx.x >> 4;
    int t  = blockIdx.x & 15;
    int tid = threadIdx.x;
    int w = tid >> 6, l = tid & 63;
    int lm = l & 15, lh = l >> 4;

    __shared__ float2 w511s[511];
    __shared__ float red[8];
    for (int i = tid; i < 511; i += 256) w511s[i] = w511[i];
    __syncthreads();

    const u16* base = x1t + (size_t)(4 * lc) * 65536;   // planes: Xr,Xi,Yr,Yi
    size_t roff = (size_t)(16 * t + lm) * 256 + 8 * lh;

    // B fragments (this block's k2-tile, all n), register-stationary.
    s16x8 ar[8], ai[8], br[8], bi[8];
    #pragma unroll
    for (int kk = 0; kk < 8; ++kk) {
        size_t off = roff + 32 * kk;
        ar[kk] = *(const s16x8*)(base + off);
        ai[kk] = *(const s16x8*)(base + 65536 + off);
        br[kk] = *(const s16x8*)(base + 131072 + off);
        bi[kk] = *(const s16x8*)(base + 196608 + off);
    }
    // Opaque write: compiler cannot rematerialize/sink these loads into the
    // kt loop (round-3 showed it does exactly that at VGPR_Count=112).
    #pragma unroll
    for (int kk = 0; kk < 8; ++kk) {
        asm volatile("" : "+v"(ar[kk]), "+v"(ai[kk]), "+v"(br[kk]), "+v"(bi[kk]));
    }

    int k2 = 16 * t + lm;
    float wgt = (k2 == 0) ? 1.f : 2.f;
    float s1 = 0.f, s2 = 0.f;

    for (int i8 = 0; i8 < 8; ++i8) {
        int kt = 8 * w + i8;
        const u16* wpa = w2f + (size_t)(kt * 2) * 4096 + l * 8;
        f32x4 crr = {0,0,0,0}, cii = {0,0,0,0}, cri = {0,0,0,0}, cir = {0,0,0,0};
        f32x4 drr = {0,0,0,0}, dii = {0,0,0,0}, dri = {0,0,0,0}, dir = {0,0,0,0};
        #pragma unroll
        for (int kk = 0; kk < 8; ++kk) {
            s16x8 wr = *(const s16x8*)(wpa + kk * 512);
            s16x8 wi = *(const s16x8*)(wpa + 4096 + kk * 512);
            crr = __builtin_amdgcn_mfma_f32_16x16x32_bf16(wr, ar[kk], crr, 0, 0, 0);
            cii = __builtin_amdgcn_mfma_f32_16x16x32_bf16(wi, ai[kk], cii, 0, 0, 0);
            cri = __builtin_amdgcn_mfma_f32_16x16x32_bf16(wr, ai[kk], cri, 0, 0, 0);
            cir = __builtin_amdgcn_mfma_f32_16x16x32_bf16(wi, ar[kk], cir, 0, 0, 0);
            drr = __builtin_amdgcn_mfma_f32_16x16x32_bf16(wr, br[kk], drr, 0, 0, 0);
            dii = __builtin_amdgcn_mfma_f32_16x16x32_bf16(wi, bi[kk], dii, 0, 0, 0);
            dri = __builtin_amdgcn_mfma_f32_16x16x32_bf16(wr, bi[kk], dri, 0, 0, 0);
            dir = __builtin_amdgcn_mfma_f32_16x16x32_bf16(wi, br[kk], dir, 0, 0, 0);
        }
        #pragma unroll
        for (int r = 0; r < 4; ++r) {
            int k1 = 16 * kt + 4 * lh + r;
            if (k1 < 511) {
                float Xr = crr[r] - cii[r], Xi = cri[r] + cir[r];
                float Yr = drr[r] - dii[r], Yi = dri[r] + dir[r];
                int p = k1 + k2; if (p >= 511) p -= 511;
                float2 wb = w511s[p];
                float Pr = Xr * Yr + Xi * Yi;
                float Pi = Xr * Yi - Xi * Yr;
                float Q  = Xr * Xr + Xi * Xi;
                float nr = Pr + EPSV * wb.x;
                float ni = Pi + EPSV * wb.y;
                float dr_ = Q + EPSV * wb.x;
                float di_ = EPSV * wb.y;
                float inv = 1.0f / (dr_ * dr_ + di_ * di_);
                s1 += wgt * (nr * dr_ + ni * di_) * inv;
                s2 += wgt * (nr * nr + ni * ni) * inv;
            }
        }
    }

    #pragma unroll
    for (int off = 32; off > 0; off >>= 1) {
        s1 += __shfl_down(s1, off);
        s2 += __shfl_down(s2, off);
    }
    if (l == 0) { red[w] = s1; red[4 + w] = s2; }
    __syncthreads();
    if (tid == 0) {
        float a1 = red[0] + red[1] + red[2] + red[3];
        float a2 = red[4] + red[5] + red[6] + red[7];
        atomicAdd(&sacc[c0 + lc], a1);
        atomicAdd(&sacc[NCH + c0 + lc], a2);
    }
}

__global__ void finalize(const float* __restrict__ s, float* __restrict__ out) {
    int t = threadIdx.x;
    float v = 0.f;
    if (t < NCH) {
        float s1 = s[t], s2 = s[NCH + t];
        v = (s2 != 0.f) ? (s1 * s1) / s2 : 0.f;
    }
    for (int off = 32; off > 0; off >>= 1) v += __shfl_down(v, off);
    if (t == 0) out[0] = 24.0f - 0.5f * v / 261121.0f;
}

// ---------------- launch ----------------
extern "C" void kernel_launch(void* const* d_in, const int* in_sizes, int n_in,
                              void* d_out, int out_size, void* d_ws, size_t ws_size,
                              hipStream_t stream) {
    const float* recon  = (const float*)d_in[0];
    const float* target = (const float*)d_in[1];
    float* out = (float*)d_out;
    char* ws = (char*)d_ws;

    const size_t OFF_W511 = 0;                       // 4096 B
    const size_t OFF_W1F  = 4096;                    // 262144 B
    const size_t OFF_W2F  = OFF_W1F + 262144;        // 524288 B
    const size_t OFF_S    = OFF_W2F + 524288;        // 512 B
    const size_t OFF_X1   = OFF_S + 512;

    float2* w511 = (float2*)(ws + OFF_W511);
    u16*    w1f  = (u16*)(ws + OFF_W1F);
    u16*    w2f  = (u16*)(ws + OFF_W2F);
    float*  sacc = (float*)(ws + OFF_S);
    u16*    x1t  = (u16*)(ws + OFF_X1);

    const size_t perch = 4ull * 65536 * 2;           // 512 KiB per channel
    size_t avail = (ws_size > OFF_X1) ? ws_size - OFF_X1 : 0;
    int chunk = (int)(avail / perch);
    if (chunk > NCH) chunk = NCH;
    if (chunk < 1) chunk = 1;

    setup<<<dim3(1024), dim3(256), 0, stream>>>(w1f, w2f, w511, sacc);

    for (int c0 = 0; c0 < NCH; c0 += chunk) {
        int cc = (NCH - c0 < chunk) ? (NCH - c0) : chunk;
        stage1<<<dim3(cc * 32), dim3(256), 0, stream>>>(target, recon, w1f, x1t, c0);
        stage2<<<dim3(cc * 16), dim3(256), 0, stream>>>(x1t, w2f, w511, sacc, c0);
    }
    finalize<<<dim3(1), dim3(64), 0, stream>>>(sacc, out);
}